// Round 4
// baseline (159.588 us; speedup 1.0000x reference)
//
#include <hip/hip_runtime.h>
#include <cmath>

// Problem constants (fixed by reference)
constexpr int Dd = 1024;   // embed dim
constexpr int Bn = 64;     // n_image == n_caption
constexpr int Sr = 36;     // regions
constexpr int Lm = 32;     // max caption length
constexpr float SMOOTH = 9.0f;
constexpr float LLSE   = 6.0f;
constexpr float EPSF   = 1e-8f;

using frag_ab = __attribute__((ext_vector_type(8))) short;  // 8 bf16 (4 VGPRs)
using frag_cd = __attribute__((ext_vector_type(4))) float;  // 4 fp32 acc

__device__ inline short f2bf(float f) {            // RNE fp32 -> bf16
  union { float f; unsigned u; } v{f};
  unsigned r = v.u + 0x7FFF + ((v.u >> 16) & 1);
  return (short)(r >> 16);
}
__device__ inline float bf2f(short h) {
  union { unsigned u; float f; } v;
  v.u = ((unsigned)(unsigned short)h) << 16;
  return v.f;
}

__device__ inline void gload16(const short* g, short* l) {
  // async global->LDS, 16B/lane; LDS dest = wave-uniform base + lane*16
  __builtin_amdgcn_global_load_lds(
      (__attribute__((address_space(1))) void*)g,
      (__attribute__((address_space(3))) void*)l, 16, 0, 0);
}

// Wave-wide (64-lane) helpers over cap_lens. All pure functions of the
// 64-entry lens array -> every block recomputes locally (graph-safe, no
// cross-block ordering).
__device__ inline int total_valid(const int* lens, int tid) {
  int v = lens[tid & 63];
#pragma unroll
  for (int o = 32; o; o >>= 1) v += __shfl_xor(v, o);
  return v;  // uniform across wave
}

// ---------------------------------------------------------------------------
// Fused prep: blockIdx ranges
//   [0, 3328)    : fp32->bf16 conversion of images (2304 blk) + W_g (1024 blk)
//   [3328, 5376) : captions: w1 norms (all rows) + bf16 conversion written to
//                  COMPACTED position off[cap]+l (valid words only)
//   [5376, 5952) : Gram, one block per (b, 4-row group)
// ---------------------------------------------------------------------------
__global__ __launch_bounds__(256) void prep_kernel(
    const float* __restrict__ images, short* __restrict__ imgbf,
    const float* __restrict__ W_g, short* __restrict__ Wbf,
    const float* __restrict__ captions, short* __restrict__ capC,
    const int* __restrict__ lens,
    float* __restrict__ w1, float* __restrict__ G)
{
  const int blk = blockIdx.x;
  const int tid = threadIdx.x;
  __shared__ float4 ref[1024];     // 4 rows x 1024 fp32 (gram branch)
  __shared__ float wsum[4];

  if (blk < 3328) {
    int i = blk * 1024 + tid * 4;
    const float* src; short* dst;
    if (i < 2304 * 1024) { src = images + i; dst = imgbf + i; }
    else { int j = i - 2304 * 1024; src = W_g + j; dst = Wbf + j; }
    float4 v = *(const float4*)src;
    short4 o;
    o.x = f2bf(v.x); o.y = f2bf(v.y); o.z = f2bf(v.z); o.w = f2bf(v.w);
    *(short4*)dst = o;
  } else if (blk < 5376) {
    const int r = blk - 3328;           // caption row 0..2047
    const int cap = r >> 5, l = r & 31;
    // per-wave exclusive prefix of lens -> off[cap]
    const int lane = tid & 63;
    int myLen = lens[lane];
    int incl = myLen;
#pragma unroll
    for (int d = 1; d < 64; d <<= 1) {
      int p = __shfl_up(incl, d);
      if (lane >= d) incl += p;
    }
    const int off = __shfl(incl - myLen, cap);   // exclusive prefix at cap
    const int len = __shfl(myLen, cap);

    float4 v = *(const float4*)(captions + (size_t)r * Dd + tid * 4);
    if (l < len) {                      // valid word -> compacted row off+l
      short4 o;
      o.x = f2bf(v.x); o.y = f2bf(v.y); o.z = f2bf(v.z); o.w = f2bf(v.w);
      *(short4*)(capC + (size_t)(off + l) * Dd + tid * 4) = o;
    }
    float s = v.x * v.x + v.y * v.y + v.z * v.z + v.w * v.w;
#pragma unroll
    for (int o2 = 32; o2; o2 >>= 1) s += __shfl_xor(s, o2);
    if ((tid & 63) == 0) wsum[tid >> 6] = s;
    __syncthreads();
    if (tid == 0) w1[r] = sqrtf(wsum[0] + wsum[1] + wsum[2] + wsum[3]);
  } else {
    // Gram: block p = (b, sg) computes rows [4sg, 4sg+4) of G_b (36x36).
    const int p = blk - 5376;          // 0..575
    const int b = p / 9, sg = p % 9;
#pragma unroll
    for (int r = 0; r < 4; r++)
      ref[r * 256 + tid] =
          ((const float4*)(images + (size_t)(b * Sr + 4 * sg + r) * Dd))[tid];
    __syncthreads();
    const int wv = tid >> 6, lane = tid & 63;
    for (int s2 = wv; s2 < Sr; s2 += 4) {
      const float4* row2 = (const float4*)(images + (size_t)(b * Sr + s2) * Dd);
      float a0 = 0.f, a1 = 0.f, a2 = 0.f, a3 = 0.f;
#pragma unroll
      for (int j = 0; j < 4; j++) {
        float4 c = row2[lane + j * 64];
        float4 r0 = ref[0 * 256 + lane + j * 64];
        float4 r1 = ref[1 * 256 + lane + j * 64];
        float4 r2 = ref[2 * 256 + lane + j * 64];
        float4 r3 = ref[3 * 256 + lane + j * 64];
        a0 += r0.x * c.x + r0.y * c.y + r0.z * c.z + r0.w * c.w;
        a1 += r1.x * c.x + r1.y * c.y + r1.z * c.z + r1.w * c.w;
        a2 += r2.x * c.x + r2.y * c.y + r2.z * c.z + r2.w * c.w;
        a3 += r3.x * c.x + r3.y * c.y + r3.z * c.z + r3.w * c.w;
      }
#pragma unroll
      for (int o = 32; o; o >>= 1) {
        a0 += __shfl_xor(a0, o); a1 += __shfl_xor(a1, o);
        a2 += __shfl_xor(a2, o); a3 += __shfl_xor(a3, o);
      }
      if (lane == 0) {
        float* gr = G + (size_t)b * Sr * Sr;
        gr[(4 * sg + 0) * Sr + s2] = a0;
        gr[(4 * sg + 1) * Sr + s2] = a1;
        gr[(4 * sg + 2) * Sr + s2] = a2;
        gr[(4 * sg + 3) * Sr + s2] = a3;
      }
    }
  }
}

// ---------------------------------------------------------------------------
// GEMM1 (E_compact = capC @ W^T): 64x64 tiles, BK=64, double-buffered,
// XOR-swizzled LDS. Grid sized for worst case (32 y-blocks); blocks beyond
// Vpad = ceil(V/64)*64 exit uniformly (V = sum of cap_lens, recomputed
// in-register). Tail rows [V,Vpad) compute on garbage capC rows; their E
// output feeds only never-read Cbig columns (element-confined).
// ---------------------------------------------------------------------------
template <int BM, int BN, int MINW>
__global__ __launch_bounds__(256, MINW) void mfma_gemm_dbuf(
    const short* __restrict__ A, const short* __restrict__ B,
    short* __restrict__ C, const int* __restrict__ lens, int K, int ldc)
{
  constexpr int FI = BM / 32;
  constexpr int FJ = BN / 32;
  __shared__ __align__(16) short LA[2][BM * 64];
  __shared__ __align__(16) short LB[2][BN * 64];

  const int t    = threadIdx.x;
  const int m0 = blockIdx.y * BM;
  const int n0 = blockIdx.x * BN;

  const int V = total_valid(lens, t);
  const int Vpad = (V + 63) & ~63;
  if (m0 >= Vpad) return;            // uniform early-exit (before barriers)

  const int lane = t & 63;
  const int w    = t >> 6;
  const int wm   = w >> 1;
  const int wn   = w & 1;

  const int rIn = t >> 3;
  const int ch  = (t & 7) ^ (rIn & 7);
  const short* gA = A + (size_t)(m0 + rIn) * K + ch * 8;
  const short* gB = B + (size_t)(n0 + rIn) * K + ch * 8;

  const int fr = lane & 15;
  const int fq = lane >> 4;
  const int p0 = fq ^ (fr & 7);

  frag_cd acc[FI][FJ] = {};

  auto stage = [&](int buf, int k0) {
#pragma unroll
    for (int j = 0; j < BM / 32; j++)
      gload16(gA + (size_t)j * 32 * K + k0, &LA[buf][j * 2048 + w * 512]);
#pragma unroll
    for (int j = 0; j < BN / 32; j++)
      gload16(gB + (size_t)j * 32 * K + k0, &LB[buf][j * 2048 + w * 512]);
  };

  stage(0, 0);
  int cur = 0;
  for (int k0 = 0; k0 < K; k0 += 64) {
    __syncthreads();
    if (k0 + 64 < K) stage(cur ^ 1, k0 + 64);

    const short* aBase = &LA[cur][(wm * (FI * 16) + fr) * 64];
    const short* bBase = &LB[cur][(wn * (FJ * 16) + fr) * 64];
#pragma unroll
    for (int th = 0; th < 2; th++) {
      const int pa = p0 ^ (th * 4);
      frag_ab af[FI], bf[FJ];
#pragma unroll
      for (int i = 0; i < FI; i++)
        af[i] = *(const frag_ab*)(aBase + i * 16 * 64 + pa * 8);
#pragma unroll
      for (int j = 0; j < FJ; j++)
        bf[j] = *(const frag_ab*)(bBase + j * 16 * 64 + pa * 8);
#pragma unroll
      for (int i = 0; i < FI; i++)
#pragma unroll
        for (int j = 0; j < FJ; j++)
          acc[i][j] = __builtin_amdgcn_mfma_f32_16x16x32_bf16(
              af[i], bf[j], acc[i][j], 0, 0, 0);
    }
    cur ^= 1;
  }

  // C/D layout: col = lane&15, row = (lane>>4)*4 + reg  [verified m89/m91]
#pragma unroll
  for (int i = 0; i < FI; i++) {
    int row = m0 + wm * (FI * 16) + i * 16 + fq * 4;
#pragma unroll
    for (int j = 0; j < FJ; j++) {
      int col = n0 + wn * (FJ * 16) + j * 16 + fr;
#pragma unroll
      for (int r = 0; r < 4; r++)
        C[(size_t)(row + r) * ldc + col] = f2bf(acc[i][j][r]);
    }
  }
}

// ---------------------------------------------------------------------------
// GEMM2 (Cbig = images @ Bcat^T): 128-thread / 2-wave blocks, block tile
// 128x64, WAVE tile 64x64 (m97-class), BK=64, single-buffer, XOR-swizzled
// LDS, 6 blocks/CU. Bcat = [E_compact (rows 0..Vpad); capC at fixed 2048].
// x-panels whose (half-local) col base >= Vpad exit uniformly -> ~36% of
// the N dimension skipped on average cap_lens.
// ---------------------------------------------------------------------------
__global__ __launch_bounds__(128, 3) void gemm2_w64(
    const short* __restrict__ A, const short* __restrict__ B,
    short* __restrict__ C, const int* __restrict__ lens, int K, int ldc)
{
  const int t    = threadIdx.x;     // 0..127
  const int m0 = blockIdx.y * 128;
  const int n0 = blockIdx.x * 64;

  const int V = total_valid(lens, t);
  const int Vpad = (V + 63) & ~63;
  const int nc = (n0 < 2048) ? n0 : (n0 - 2048);
  if (nc >= Vpad) return;            // uniform early-exit (before barriers)

  __shared__ __align__(16) short As[128 * 64];
  __shared__ __align__(16) short Bs[64 * 64];

  const int lane = t & 63;
  const int w    = t >> 6;          // wave 0..1 (m-halves)

  const int rIn = t >> 3;
  const int ch  = (t & 7) ^ (rIn & 7);
  const short* gA = A + (size_t)(m0 + rIn) * K + ch * 8;
  const short* gB = B + (size_t)(n0 + rIn) * K + ch * 8;

  const int fr = lane & 15;
  const int fq = lane >> 4;
  const int p0 = fq ^ (fr & 7);

  frag_cd acc[4][4] = {};

  for (int k0 = 0; k0 < K; k0 += 64) {
    __syncthreads();                 // prev-iter LDS readers done
#pragma unroll
    for (int j = 0; j < 8; j++)      // A: 128 rows, 16 per issue
      gload16(gA + (size_t)j * 16 * K + k0, As + j * 1024 + w * 512);
#pragma unroll
    for (int j = 0; j < 4; j++)      // B: 64 rows
      gload16(gB + (size_t)j * 16 * K + k0, Bs + j * 1024 + w * 512);
    __syncthreads();                 // barrier drains vmcnt -> tile published

    const short* aBase = As + (w * 64 + fr) * 64;
    const short* bBase = Bs + fr * 64;
#pragma unroll
    for (int th = 0; th < 2; th++) {
      const int pa = p0 ^ (th * 4);  // swizzled chunk pos for this k-half
      frag_ab af[4], bf[4];
#pragma unroll
      for (int i = 0; i < 4; i++)
        af[i] = *(const frag_ab*)(aBase + i * 16 * 64 + pa * 8);
#pragma unroll
      for (int j = 0; j < 4; j++)
        bf[j] = *(const frag_ab*)(bBase + j * 16 * 64 + pa * 8);
#pragma unroll
      for (int i = 0; i < 4; i++)
#pragma unroll
        for (int j = 0; j < 4; j++)
          acc[i][j] = __builtin_amdgcn_mfma_f32_16x16x32_bf16(
              af[i], bf[j], acc[i][j], 0, 0, 0);
    }
  }

  // C/D layout: col = lane&15, row = (lane>>4)*4 + reg  [verified m89/m91]
#pragma unroll
  for (int i = 0; i < 4; i++) {
    int row = m0 + w * 64 + i * 16 + fq * 4;
#pragma unroll
    for (int j = 0; j < 4; j++) {
      int col = n0 + j * 16 + fr;
#pragma unroll
      for (int r = 0; r < 4; r++)
        C[(size_t)(row + r) * ldc + col] = f2bf(acc[i][j][r]);
    }
  }
}

// ---------------------------------------------------------------------------
// Finalize: block = (image b, 4 captions); ONE WAVE PER (b,cap) PAIR.
// Reads compacted Cbig columns off[cap]+l (E-half) / 2048+off[cap]+l
// (cap-half), guarded by l<len (invalid lanes get exact 0, matching the
// reference mask semantics).
// ---------------------------------------------------------------------------
__global__ __launch_bounds__(256) void finalize_kernel(
    const short* __restrict__ Cbig, const float* __restrict__ G,
    const float* __restrict__ w1arr, const int* __restrict__ lens,
    float* __restrict__ out)
{
  const int b   = blockIdx.x;        // image
  const int cg  = blockIdx.y;        // caption group of 4
  const int t   = threadIdx.x;
  const int wv  = t >> 6;            // wave -> caption within group
  const int lane = t & 63;
  const int cap = cg * 4 + wv;
  const int l = lane & 31;
  const int s0 = lane >> 5;

  __shared__ float att[4][Sr][Lm];   // fp32 working attn, per wave
  __shared__ short cims[4][Sr][Lm];  // bf16 cap.img dots, per wave
  __shared__ float Gs[Sr][Sr];       // Gram, shared across waves

  for (int i = t; i < Sr * Sr; i += 256)
    Gs[i / Sr][i % Sr] = G[(size_t)b * Sr * Sr + i];

  // off[cap] via 64-lane exclusive scan of lens
  int myLen = lens[lane];
  int incl = myLen;
#pragma unroll
  for (int d = 1; d < 64; d <<= 1) {
    int p = __shfl_up(incl, d);
    if (lane >= d) incl += p;
  }
  const int off = __shfl(incl - myLen, cap);
  const int len = __shfl(myLen, cap);

  // load + leaky-relu + mask (2 s-rows per step: s = 2k + s0)
#pragma unroll
  for (int k = 0; k < 18; k++) {
    int s = k * 2 + s0;
    size_t row = (size_t)(b * Sr + s) * 4096;
    float x = 0.f;
    short cv = 0;
    if (l < len) {
      x = bf2f(Cbig[row + off + l]);
      x = x > 0.f ? x : 0.1f * x;
      cv = Cbig[row + 2048 + off + l];
    }
    att[wv][s][l] = x;
    cims[wv][s][l] = cv;
  }
  __syncthreads();

  // l2 norm over words l, per region s (half-wave reduction, width 32)
#pragma unroll
  for (int k = 0; k < 18; k++) {
    int s = k * 2 + s0;
    float v = att[wv][s][l];
    float ss = v * v;
#pragma unroll
    for (int o = 16; o; o >>= 1) ss += __shfl_xor(ss, o);
    att[wv][s][l] = v * (1.f / (sqrtf(ss) + EPSF));
  }
  __syncthreads();

  // softmax over regions s, per word l (half 0 only)
  if (s0 == 0) {
    float m = -1e30f;
#pragma unroll
    for (int s = 0; s < Sr; s++) m = fmaxf(m, att[wv][s][l]);
    m *= SMOOTH;
    float sum = 0.f;
#pragma unroll
    for (int s = 0; s < Sr; s++) {
      float e = expf(SMOOTH * att[wv][s][l] - m);
      att[wv][s][l] = e; sum += e;
    }
    float inv = 1.f / sum;
#pragma unroll
    for (int s = 0; s < Sr; s++) att[wv][s][l] *= inv;
  }
  __syncthreads();

  // a into registers; w12 & w2 = a^T G a with outer s split across halves
  float a_reg[Sr];
#pragma unroll
  for (int s = 0; s < Sr; s++) a_reg[s] = att[wv][s][l];
  float w12 = 0.f, w2 = 0.f;
  for (int s = s0 * 18; s < s0 * 18 + 18; s++) {
    float a = a_reg[s];
    w12 += a * bf2f(cims[wv][s][l]);
    float tt = 0.f;
    const float4* grow = (const float4*)Gs[s];
#pragma unroll
    for (int q = 0; q < 9; q++) {
      float4 g = grow[q];                        // broadcast read
      tt += g.x * a_reg[q * 4] + g.y * a_reg[q * 4 + 1] +
            g.z * a_reg[q * 4 + 2] + g.w * a_reg[q * 4 + 3];
    }
    w2 += a * tt;
  }
  w12 += __shfl_xor(w12, 32);
  w2  += __shfl_xor(w2, 32);

  // cosine + LogSumExp over valid words (width-32 reduce; halves identical)
  float w1v = w1arr[cap * Lm + l];
  float denom = fmaxf(w1v * sqrtf(fmaxf(w2, 0.f)), EPSF);
  float rs = w12 / denom;
  float z = (l < len) ? rs * LLSE : -1e30f;
  float m = z;
#pragma unroll
  for (int o = 16; o; o >>= 1) m = fmaxf(m, __shfl_xor(m, o));
  float e = expf(z - m);
#pragma unroll
  for (int o = 16; o; o >>= 1) e += __shfl_xor(e, o);
  if (lane == 0) out[(size_t)b * Bn + cap] = (m + logf(e)) / LLSE;
}

// ---------------------------------------------------------------------------
extern "C" void kernel_launch(void* const* d_in, const int* in_sizes, int n_in,
                              void* d_out, int out_size, void* d_ws, size_t ws_size,
                              hipStream_t stream)
{
  const float* images   = (const float*)d_in[0];  // (64,36,1024)
  const float* captions = (const float*)d_in[1];  // (64,32,1024)
  const int*   cap_lens = (const int*)d_in[2];    // (64,)
  const float* W_g      = (const float*)d_in[3];  // (1024,1024)
  float* out = (float*)d_out;                     // (64,64)

  // Workspace (~34.4 MB):
  short* imgbf = (short*)d_ws;                          // 2304*1024 bf16
  short* Bcat  = imgbf + (size_t)2304 * 1024;           // 4096*1024 bf16:
                                                        //  rows [0,2048): E_compact (valid V rows)
                                                        //  rows [2048,4096): capC (compacted captions)
  short* capC  = Bcat + (size_t)2048 * 1024;
  short* Wbf   = Bcat + (size_t)4096 * 1024;            // 1024*1024 bf16
  short* Cbig  = Wbf + (size_t)1024 * 1024;             // 2304*4096 bf16
  float* Gram  = (float*)(Cbig + (size_t)2304 * 4096);  // 64*36*36 fp32
  float* w1a   = Gram + (size_t)Bn * Sr * Sr;           // 2048 fp32

  // conversions (captions -> compacted) + w1 + gram fused (5952 blocks)
  prep_kernel<<<5952, 256, 0, stream>>>(
      images, imgbf, W_g, Wbf, captions, capC, cap_lens, w1a, Gram);

  // E_compact = capC @ W_g^T (V x 1024 x 1024): 64x64 tiles, static
  // worst-case grid, early-exit past Vpad (~36% skipped on average)
  mfma_gemm_dbuf<64, 64, 4><<<dim3(1024 / 64, 2048 / 64), 256, 0, stream>>>(
      capC, Wbf, Bcat, cap_lens, Dd, 1024);
  // Cbig = images @ Bcat^T: 128x64 blocks, 2 waves, wave tile 64x64,
  // 6 blocks/CU; x-panels past Vpad (per half) early-exit
  gemm2_w64<<<dim3(4096 / 64, 2304 / 128), 128, 0, stream>>>(
      imgbf, Bcat, Cbig, cap_lens, Dd, 4096);

  // finalize: block = image x 4 captions, one wave per (b,cap)
  finalize_kernel<<<dim3(Bn, Bn / 4), 256, 0, stream>>>(
      Cbig, Gram, w1a, cap_lens, out);
}

// Round 5
// 153.570 us; speedup vs baseline: 1.0392x; 1.0392x over previous
//
#include <hip/hip_runtime.h>
#include <cmath>

// Problem constants (fixed by reference)
constexpr int Dd = 1024;   // embed dim
constexpr int Bn = 64;     // n_image == n_caption
constexpr int Sr = 36;     // regions
constexpr int Lm = 32;     // max caption length
constexpr float SMOOTH = 9.0f;
constexpr float LLSE   = 6.0f;
constexpr float EPSF   = 1e-8f;

using frag_ab = __attribute__((ext_vector_type(8))) short;  // 8 bf16 (4 VGPRs)
using frag_cd = __attribute__((ext_vector_type(4))) float;  // 4 fp32 acc

__device__ inline short f2bf(float f) {            // RNE fp32 -> bf16
  union { float f; unsigned u; } v{f};
  unsigned r = v.u + 0x7FFF + ((v.u >> 16) & 1);
  return (short)(r >> 16);
}
__device__ inline float bf2f(short h) {
  union { unsigned u; float f; } v;
  v.u = ((unsigned)(unsigned short)h) << 16;
  return v.f;
}

__device__ inline void gload16(const short* g, short* l) {
  // async global->LDS, 16B/lane; LDS dest = wave-uniform base + lane*16
  __builtin_amdgcn_global_load_lds(
      (__attribute__((address_space(1))) void*)g,
      (__attribute__((address_space(3))) void*)l, 16, 0, 0);
}

// Wave-wide (64-lane) helpers over cap_lens. Pure functions of the 64-entry
// lens array -> every block recomputes locally (graph-safe, no cross-block
// ordering assumptions).
__device__ inline int total_valid(const int* lens, int tid) {
  int v = lens[tid & 63];
#pragma unroll
  for (int o = 32; o; o >>= 1) v += __shfl_xor(v, o);
  return v;  // uniform across wave
}

// ---------------------------------------------------------------------------
// Fused prep: blockIdx ranges
//   [0, 3328)    : fp32->bf16 conversion of images (2304 blk) + W_g (1024 blk)
//   [3328, 5376) : captions: w1 norms (all rows) + bf16 conversion written to
//                  COMPACTED position off[cap]+l (valid words only)
//   [5376, 5952) : Gram, one block per (b, 4-row group)
// ---------------------------------------------------------------------------
__global__ __launch_bounds__(256) void prep_kernel(
    const float* __restrict__ images, short* __restrict__ imgbf,
    const float* __restrict__ W_g, short* __restrict__ Wbf,
    const float* __restrict__ captions, short* __restrict__ capC,
    const int* __restrict__ lens,
    float* __restrict__ w1, float* __restrict__ G)
{
  const int blk = blockIdx.x;
  const int tid = threadIdx.x;
  __shared__ float4 ref[1024];     // 4 rows x 1024 fp32 (gram branch)
  __shared__ float wsum[4];

  if (blk < 3328) {
    int i = blk * 1024 + tid * 4;
    const float* src; short* dst;
    if (i < 2304 * 1024) { src = images + i; dst = imgbf + i; }
    else { int j = i - 2304 * 1024; src = W_g + j; dst = Wbf + j; }
    float4 v = *(const float4*)src;
    short4 o;
    o.x = f2bf(v.x); o.y = f2bf(v.y); o.z = f2bf(v.z); o.w = f2bf(v.w);
    *(short4*)dst = o;
  } else if (blk < 5376) {
    const int r = blk - 3328;           // caption row 0..2047
    const int cap = r >> 5, l = r & 31;
    // per-wave exclusive prefix of lens -> off[cap]
    const int lane = tid & 63;
    int myLen = lens[lane];
    int incl = myLen;
#pragma unroll
    for (int d = 1; d < 64; d <<= 1) {
      int p = __shfl_up(incl, d);
      if (lane >= d) incl += p;
    }
    const int off = __shfl(incl - myLen, cap);   // exclusive prefix at cap
    const int len = __shfl(myLen, cap);

    float4 v = *(const float4*)(captions + (size_t)r * Dd + tid * 4);
    if (l < len) {                      // valid word -> compacted row off+l
      short4 o;
      o.x = f2bf(v.x); o.y = f2bf(v.y); o.z = f2bf(v.z); o.w = f2bf(v.w);
      *(short4*)(capC + (size_t)(off + l) * Dd + tid * 4) = o;
    }
    float s = v.x * v.x + v.y * v.y + v.z * v.z + v.w * v.w;
#pragma unroll
    for (int o2 = 32; o2; o2 >>= 1) s += __shfl_xor(s, o2);
    if ((tid & 63) == 0) wsum[tid >> 6] = s;
    __syncthreads();
    if (tid == 0) w1[r] = sqrtf(wsum[0] + wsum[1] + wsum[2] + wsum[3]);
  } else {
    // Gram: block p = (b, sg) computes rows [4sg, 4sg+4) of G_b (36x36).
    const int p = blk - 5376;          // 0..575
    const int b = p / 9, sg = p % 9;
#pragma unroll
    for (int r = 0; r < 4; r++)
      ref[r * 256 + tid] =
          ((const float4*)(images + (size_t)(b * Sr + 4 * sg + r) * Dd))[tid];
    __syncthreads();
    const int wv = tid >> 6, lane = tid & 63;
    for (int s2 = wv; s2 < Sr; s2 += 4) {
      const float4* row2 = (const float4*)(images + (size_t)(b * Sr + s2) * Dd);
      float a0 = 0.f, a1 = 0.f, a2 = 0.f, a3 = 0.f;
#pragma unroll
      for (int j = 0; j < 4; j++) {
        float4 c = row2[lane + j * 64];
        float4 r0 = ref[0 * 256 + lane + j * 64];
        float4 r1 = ref[1 * 256 + lane + j * 64];
        float4 r2 = ref[2 * 256 + lane + j * 64];
        float4 r3 = ref[3 * 256 + lane + j * 64];
        a0 += r0.x * c.x + r0.y * c.y + r0.z * c.z + r0.w * c.w;
        a1 += r1.x * c.x + r1.y * c.y + r1.z * c.z + r1.w * c.w;
        a2 += r2.x * c.x + r2.y * c.y + r2.z * c.z + r2.w * c.w;
        a3 += r3.x * c.x + r3.y * c.y + r3.z * c.z + r3.w * c.w;
      }
#pragma unroll
      for (int o = 32; o; o >>= 1) {
        a0 += __shfl_xor(a0, o); a1 += __shfl_xor(a1, o);
        a2 += __shfl_xor(a2, o); a3 += __shfl_xor(a3, o);
      }
      if (lane == 0) {
        float* gr = G + (size_t)b * Sr * Sr;
        gr[(4 * sg + 0) * Sr + s2] = a0;
        gr[(4 * sg + 1) * Sr + s2] = a1;
        gr[(4 * sg + 2) * Sr + s2] = a2;
        gr[(4 * sg + 3) * Sr + s2] = a3;
      }
    }
  }
}

// ---------------------------------------------------------------------------
// GEMM1 (E_compact = capC @ W^T): 64x64 tiles, BK=64, double-buffered,
// XOR-swizzled LDS. DENSE TILE REMAP: block wid takes the wid-th working
// tile of the compacted M-range (Vpad rows); wid >= nTiles exits. Working
// tiles land on consecutive block IDs -> even CU distribution (R4's striped
// early-exit left max-loaded CUs unchanged -> null result).
// ---------------------------------------------------------------------------
template <int BM, int BN, int MINW>
__global__ __launch_bounds__(256, MINW) void mfma_gemm_dbuf(
    const short* __restrict__ A, const short* __restrict__ B,
    short* __restrict__ C, const int* __restrict__ lens, int K, int ldc)
{
  constexpr int FI = BM / 32;
  constexpr int FJ = BN / 32;
  __shared__ __align__(16) short LA[2][BM * 64];
  __shared__ __align__(16) short LB[2][BN * 64];

  const int t   = threadIdx.x;
  const int wid = blockIdx.y * gridDim.x + blockIdx.x;

  const int V = total_valid(lens, t);
  const int mt = ((V + 63) & ~63) >> 6;   // working m-tiles (BM=64)
  if (wid >= mt * 16) return;             // uniform exit, before any barrier
  // 16 n-tiles (N=1024, BN=64); consecutive wids share the m-stripe
  const int m0 = (wid >> 4) * BM;
  const int n0 = (wid & 15) * BN;

  const int lane = t & 63;
  const int w    = t >> 6;
  const int wm   = w >> 1;
  const int wn   = w & 1;

  const int rIn = t >> 3;
  const int ch  = (t & 7) ^ (rIn & 7);
  const short* gA = A + (size_t)(m0 + rIn) * K + ch * 8;
  const short* gB = B + (size_t)(n0 + rIn) * K + ch * 8;

  const int fr = lane & 15;
  const int fq = lane >> 4;
  const int p0 = fq ^ (fr & 7);

  frag_cd acc[FI][FJ] = {};

  auto stage = [&](int buf, int k0) {
#pragma unroll
    for (int j = 0; j < BM / 32; j++)
      gload16(gA + (size_t)j * 32 * K + k0, &LA[buf][j * 2048 + w * 512]);
#pragma unroll
    for (int j = 0; j < BN / 32; j++)
      gload16(gB + (size_t)j * 32 * K + k0, &LB[buf][j * 2048 + w * 512]);
  };

  stage(0, 0);
  int cur = 0;
  for (int k0 = 0; k0 < K; k0 += 64) {
    __syncthreads();
    if (k0 + 64 < K) stage(cur ^ 1, k0 + 64);

    const short* aBase = &LA[cur][(wm * (FI * 16) + fr) * 64];
    const short* bBase = &LB[cur][(wn * (FJ * 16) + fr) * 64];
#pragma unroll
    for (int th = 0; th < 2; th++) {
      const int pa = p0 ^ (th * 4);
      frag_ab af[FI], bf[FJ];
#pragma unroll
      for (int i = 0; i < FI; i++)
        af[i] = *(const frag_ab*)(aBase + i * 16 * 64 + pa * 8);
#pragma unroll
      for (int j = 0; j < FJ; j++)
        bf[j] = *(const frag_ab*)(bBase + j * 16 * 64 + pa * 8);
#pragma unroll
      for (int i = 0; i < FI; i++)
#pragma unroll
        for (int j = 0; j < FJ; j++)
          acc[i][j] = __builtin_amdgcn_mfma_f32_16x16x32_bf16(
              af[i], bf[j], acc[i][j], 0, 0, 0);
    }
    cur ^= 1;
  }

  // C/D layout: col = lane&15, row = (lane>>4)*4 + reg  [verified m89/m91]
#pragma unroll
  for (int i = 0; i < FI; i++) {
    int row = m0 + wm * (FI * 16) + i * 16 + fq * 4;
#pragma unroll
    for (int j = 0; j < FJ; j++) {
      int col = n0 + wn * (FJ * 16) + j * 16 + fr;
#pragma unroll
      for (int r = 0; r < 4; r++)
        C[(size_t)(row + r) * ldc + col] = f2bf(acc[i][j][r]);
    }
  }
}

// ---------------------------------------------------------------------------
// GEMM2 (Cbig = images @ Bcat^T): 128-thread / 2-wave blocks, block tile
// 128x64, WAVE tile 64x64 (m97-class), BK=64, single-buffer, XOR-swizzled
// LDS, 6 blocks/CU. Bcat = [E_compact rows 0..Vpad; capC at fixed 2048].
// DENSE TILE REMAP over the compacted N-domain: nx working panels per half,
// 2*nx*18 working tiles assigned to consecutive block IDs; the rest exit.
// ---------------------------------------------------------------------------
__global__ __launch_bounds__(128, 3) void gemm2_w64(
    const short* __restrict__ A, const short* __restrict__ B,
    short* __restrict__ C, const int* __restrict__ lens, int K, int ldc)
{
  const int t   = threadIdx.x;     // 0..127
  const int wid = blockIdx.y * gridDim.x + blockIdx.x;

  const int V  = total_valid(lens, t);
  const int nx = ((V + 63) & ~63) >> 6;   // working 64-col panels per half
  const int tw = 2 * nx;                  // panels per 128-row m-stripe
  if (wid >= tw * 18) return;             // uniform exit, before any barrier
  const int y  = wid / tw;                // m-stripe (consecutive wids share)
  const int r  = wid - y * tw;
  const int xl = (r < nx) ? r : r - nx;
  const int n0 = ((r < nx) ? 0 : 2048) + xl * 64;
  const int m0 = y * 128;

  __shared__ __align__(16) short As[128 * 64];
  __shared__ __align__(16) short Bs[64 * 64];

  const int lane = t & 63;
  const int w    = t >> 6;          // wave 0..1 (m-halves)

  const int rIn = t >> 3;
  const int ch  = (t & 7) ^ (rIn & 7);
  const short* gA = A + (size_t)(m0 + rIn) * K + ch * 8;
  const short* gB = B + (size_t)(n0 + rIn) * K + ch * 8;

  const int fr = lane & 15;
  const int fq = lane >> 4;
  const int p0 = fq ^ (fr & 7);

  frag_cd acc[4][4] = {};

  for (int k0 = 0; k0 < K; k0 += 64) {
    __syncthreads();                 // prev-iter LDS readers done
#pragma unroll
    for (int j = 0; j < 8; j++)      // A: 128 rows, 16 per issue
      gload16(gA + (size_t)j * 16 * K + k0, As + j * 1024 + w * 512);
#pragma unroll
    for (int j = 0; j < 4; j++)      // B: 64 rows
      gload16(gB + (size_t)j * 16 * K + k0, Bs + j * 1024 + w * 512);
    __syncthreads();                 // barrier drains vmcnt -> tile published

    const short* aBase = As + (w * 64 + fr) * 64;
    const short* bBase = Bs + fr * 64;
#pragma unroll
    for (int th = 0; th < 2; th++) {
      const int pa = p0 ^ (th * 4);  // swizzled chunk pos for this k-half
      frag_ab af[4], bf[4];
#pragma unroll
      for (int i = 0; i < 4; i++)
        af[i] = *(const frag_ab*)(aBase + i * 16 * 64 + pa * 8);
#pragma unroll
      for (int j = 0; j < 4; j++)
        bf[j] = *(const frag_ab*)(bBase + j * 16 * 64 + pa * 8);
#pragma unroll
      for (int i = 0; i < 4; i++)
#pragma unroll
        for (int j = 0; j < 4; j++)
          acc[i][j] = __builtin_amdgcn_mfma_f32_16x16x32_bf16(
              af[i], bf[j], acc[i][j], 0, 0, 0);
    }
  }

  // C/D layout: col = lane&15, row = (lane>>4)*4 + reg  [verified m89/m91]
#pragma unroll
  for (int i = 0; i < 4; i++) {
    int row = m0 + w * 64 + i * 16 + fq * 4;
#pragma unroll
    for (int j = 0; j < 4; j++) {
      int col = n0 + j * 16 + fr;
#pragma unroll
      for (int r2 = 0; r2 < 4; r2++)
        C[(size_t)(row + r2) * ldc + col] = f2bf(acc[i][j][r2]);
    }
  }
}

// ---------------------------------------------------------------------------
// Finalize: block = (image b, 4 captions); ONE WAVE PER (b,cap) PAIR.
// Reads compacted Cbig columns off[cap]+l (E-half) / 2048+off[cap]+l
// (cap-half), guarded by l<len (invalid lanes get exact 0, matching the
// reference mask semantics).
// ---------------------------------------------------------------------------
__global__ __launch_bounds__(256) void finalize_kernel(
    const short* __restrict__ Cbig, const float* __restrict__ G,
    const float* __restrict__ w1arr, const int* __restrict__ lens,
    float* __restrict__ out)
{
  const int b   = blockIdx.x;        // image
  const int cg  = blockIdx.y;        // caption group of 4
  const int t   = threadIdx.x;
  const int wv  = t >> 6;            // wave -> caption within group
  const int lane = t & 63;
  const int cap = cg * 4 + wv;
  const int l = lane & 31;
  const int s0 = lane >> 5;

  __shared__ float att[4][Sr][Lm];   // fp32 working attn, per wave
  __shared__ short cims[4][Sr][Lm];  // bf16 cap.img dots, per wave
  __shared__ float Gs[Sr][Sr];       // Gram, shared across waves

  for (int i = t; i < Sr * Sr; i += 256)
    Gs[i / Sr][i % Sr] = G[(size_t)b * Sr * Sr + i];

  // off[cap] via 64-lane exclusive scan of lens
  int myLen = lens[lane];
  int incl = myLen;
#pragma unroll
  for (int d = 1; d < 64; d <<= 1) {
    int p = __shfl_up(incl, d);
    if (lane >= d) incl += p;
  }
  const int off = __shfl(incl - myLen, cap);
  const int len = __shfl(myLen, cap);

  // load + leaky-relu + mask (2 s-rows per step: s = 2k + s0)
#pragma unroll
  for (int k = 0; k < 18; k++) {
    int s = k * 2 + s0;
    size_t row = (size_t)(b * Sr + s) * 4096;
    float x = 0.f;
    short cv = 0;
    if (l < len) {
      x = bf2f(Cbig[row + off + l]);
      x = x > 0.f ? x : 0.1f * x;
      cv = Cbig[row + 2048 + off + l];
    }
    att[wv][s][l] = x;
    cims[wv][s][l] = cv;
  }
  __syncthreads();

  // l2 norm over words l, per region s (half-wave reduction, width 32)
#pragma unroll
  for (int k = 0; k < 18; k++) {
    int s = k * 2 + s0;
    float v = att[wv][s][l];
    float ss = v * v;
#pragma unroll
    for (int o = 16; o; o >>= 1) ss += __shfl_xor(ss, o);
    att[wv][s][l] = v * (1.f / (sqrtf(ss) + EPSF));
  }
  __syncthreads();

  // softmax over regions s, per word l (half 0 only)
  if (s0 == 0) {
    float m = -1e30f;
#pragma unroll
    for (int s = 0; s < Sr; s++) m = fmaxf(m, att[wv][s][l]);
    m *= SMOOTH;
    float sum = 0.f;
#pragma unroll
    for (int s = 0; s < Sr; s++) {
      float e = expf(SMOOTH * att[wv][s][l] - m);
      att[wv][s][l] = e; sum += e;
    }
    float inv = 1.f / sum;
#pragma unroll
    for (int s = 0; s < Sr; s++) att[wv][s][l] *= inv;
  }
  __syncthreads();

  // a into registers; w12 & w2 = a^T G a with outer s split across halves
  float a_reg[Sr];
#pragma unroll
  for (int s = 0; s < Sr; s++) a_reg[s] = att[wv][s][l];
  float w12 = 0.f, w2 = 0.f;
  for (int s = s0 * 18; s < s0 * 18 + 18; s++) {
    float a = a_reg[s];
    w12 += a * bf2f(cims[wv][s][l]);
    float tt = 0.f;
    const float4* grow = (const float4*)Gs[s];
#pragma unroll
    for (int q = 0; q < 9; q++) {
      float4 g = grow[q];                        // broadcast read
      tt += g.x * a_reg[q * 4] + g.y * a_reg[q * 4 + 1] +
            g.z * a_reg[q * 4 + 2] + g.w * a_reg[q * 4 + 3];
    }
    w2 += a * tt;
  }
  w12 += __shfl_xor(w12, 32);
  w2  += __shfl_xor(w2, 32);

  // cosine + LogSumExp over valid words (width-32 reduce; halves identical)
  float w1v = w1arr[cap * Lm + l];
  float denom = fmaxf(w1v * sqrtf(fmaxf(w2, 0.f)), EPSF);
  float rs = w12 / denom;
  float z = (l < len) ? rs * LLSE : -1e30f;
  float m = z;
#pragma unroll
  for (int o = 16; o; o >>= 1) m = fmaxf(m, __shfl_xor(m, o));
  float e = expf(z - m);
#pragma unroll
  for (int o = 16; o; o >>= 1) e += __shfl_xor(e, o);
  if (lane == 0) out[(size_t)b * Bn + cap] = (m + logf(e)) / LLSE;
}

// ---------------------------------------------------------------------------
extern "C" void kernel_launch(void* const* d_in, const int* in_sizes, int n_in,
                              void* d_out, int out_size, void* d_ws, size_t ws_size,
                              hipStream_t stream)
{
  const float* images   = (const float*)d_in[0];  // (64,36,1024)
  const float* captions = (const float*)d_in[1];  // (64,32,1024)
  const int*   cap_lens = (const int*)d_in[2];    // (64,)
  const float* W_g      = (const float*)d_in[3];  // (1024,1024)
  float* out = (float*)d_out;                     // (64,64)

  // Workspace (~34.4 MB):
  short* imgbf = (short*)d_ws;                          // 2304*1024 bf16
  short* Bcat  = imgbf + (size_t)2304 * 1024;           // 4096*1024 bf16:
                                                        //  rows [0,2048): E_compact (valid V rows)
                                                        //  rows [2048,4096): capC (compacted captions)
  short* capC  = Bcat + (size_t)2048 * 1024;
  short* Wbf   = Bcat + (size_t)4096 * 1024;            // 1024*1024 bf16
  short* Cbig  = Wbf + (size_t)1024 * 1024;             // 2304*4096 bf16
  float* Gram  = (float*)(Cbig + (size_t)2304 * 4096);  // 64*36*36 fp32
  float* w1a   = Gram + (size_t)Bn * Sr * Sr;           // 2048 fp32

  // conversions (captions -> compacted) + w1 + gram fused (5952 blocks)
  prep_kernel<<<5952, 256, 0, stream>>>(
      images, imgbf, W_g, Wbf, captions, capC, cap_lens, w1a, Gram);

  // E_compact = capC @ W_g^T (V x 1024 x 1024): 64x64 tiles, dense remap
  // over Vpad rows; ~36% of blocks exit as a contiguous ID range
  mfma_gemm_dbuf<64, 64, 4><<<dim3(1024 / 64, 2048 / 64), 256, 0, stream>>>(
      capC, Wbf, Bcat, cap_lens, Dd, 1024);
  // Cbig = images @ Bcat^T: 128x64 blocks, 2 waves, wave tile 64x64,
  // 6 blocks/CU; dense remap over 2*nx*18 working tiles
  gemm2_w64<<<dim3(4096 / 64, 2304 / 128), 128, 0, stream>>>(
      imgbf, Bcat, Cbig, cap_lens, Dd, 4096);

  // finalize: block = image x 4 captions, one wave per (b,cap)
  finalize_kernel<<<dim3(Bn, Bn / 4), 256, 0, stream>>>(
      Cbig, Gram, w1a, cap_lens, out);
}

// Round 7
// 153.275 us; speedup vs baseline: 1.0412x; 1.0019x over previous
//
#include <hip/hip_runtime.h>
#include <cmath>

// Problem constants (fixed by reference)
constexpr int Dd = 1024;   // embed dim
constexpr int Bn = 64;     // n_image == n_caption
constexpr int Sr = 36;     // regions
constexpr int Lm = 32;     // max caption length
constexpr float SMOOTH = 9.0f;
constexpr float LLSE   = 6.0f;
constexpr float EPSF   = 1e-8f;

using frag_ab = __attribute__((ext_vector_type(8))) short;  // 8 bf16 (4 VGPRs)
using frag_cd = __attribute__((ext_vector_type(4))) float;  // 4 fp32 acc

__device__ inline short f2bf(float f) {            // RNE fp32 -> bf16
  union { float f; unsigned u; } v{f};
  unsigned r = v.u + 0x7FFF + ((v.u >> 16) & 1);
  return (short)(r >> 16);
}
__device__ inline float bf2f(short h) {
  union { unsigned u; float f; } v;
  v.u = ((unsigned)(unsigned short)h) << 16;
  return v.f;
}

__device__ inline void gload16(const short* g, short* l) {
  // async global->LDS, 16B/lane; LDS dest = wave-uniform base + lane*16
  __builtin_amdgcn_global_load_lds(
      (__attribute__((address_space(1))) void*)g,
      (__attribute__((address_space(3))) void*)l, 16, 0, 0);
}

// Wave-wide (64-lane) helpers over cap_lens. Pure functions of the 64-entry
// lens array -> every block recomputes locally (graph-safe, no cross-block
// ordering assumptions).
__device__ inline int total_valid(const int* lens, int tid) {
  int v = lens[tid & 63];
#pragma unroll
  for (int o = 32; o; o >>= 1) v += __shfl_xor(v, o);
  return v;  // uniform across wave
}

// ---------------------------------------------------------------------------
// Fused prep: blockIdx ranges
//   [0, 3328)    : fp32->bf16 conversion of images (2304 blk) + W_g (1024 blk)
//   [3328, 5376) : captions: w1 norms (all rows) + bf16 conversion written to
//                  COMPACTED position off[cap]+l (valid words only)
//   [5376, 5952) : Gram, one block per (b, 4-row group)
// ---------------------------------------------------------------------------
__global__ __launch_bounds__(256) void prep_kernel(
    const float* __restrict__ images, short* __restrict__ imgbf,
    const float* __restrict__ W_g, short* __restrict__ Wbf,
    const float* __restrict__ captions, short* __restrict__ capC,
    const int* __restrict__ lens,
    float* __restrict__ w1, float* __restrict__ G)
{
  const int blk = blockIdx.x;
  const int tid = threadIdx.x;
  __shared__ float4 ref[1024];     // 4 rows x 1024 fp32 (gram branch)
  __shared__ float wsum[4];

  if (blk < 3328) {
    int i = blk * 1024 + tid * 4;
    const float* src; short* dst;
    if (i < 2304 * 1024) { src = images + i; dst = imgbf + i; }
    else { int j = i - 2304 * 1024; src = W_g + j; dst = Wbf + j; }
    float4 v = *(const float4*)src;
    short4 o;
    o.x = f2bf(v.x); o.y = f2bf(v.y); o.z = f2bf(v.z); o.w = f2bf(v.w);
    *(short4*)dst = o;
  } else if (blk < 5376) {
    const int r = blk - 3328;           // caption row 0..2047
    const int cap = r >> 5, l = r & 31;
    // per-wave exclusive prefix of lens -> off[cap]
    const int lane = tid & 63;
    int myLen = lens[lane];
    int incl = myLen;
#pragma unroll
    for (int d = 1; d < 64; d <<= 1) {
      int p = __shfl_up(incl, d);
      if (lane >= d) incl += p;
    }
    const int off = __shfl(incl - myLen, cap);   // exclusive prefix at cap
    const int len = __shfl(myLen, cap);

    float4 v = *(const float4*)(captions + (size_t)r * Dd + tid * 4);
    if (l < len) {                      // valid word -> compacted row off+l
      short4 o;
      o.x = f2bf(v.x); o.y = f2bf(v.y); o.z = f2bf(v.z); o.w = f2bf(v.w);
      *(short4*)(capC + (size_t)(off + l) * Dd + tid * 4) = o;
    }
    float s = v.x * v.x + v.y * v.y + v.z * v.z + v.w * v.w;
#pragma unroll
    for (int o2 = 32; o2; o2 >>= 1) s += __shfl_xor(s, o2);
    if ((tid & 63) == 0) wsum[tid >> 6] = s;
    __syncthreads();
    if (tid == 0) w1[r] = sqrtf(wsum[0] + wsum[1] + wsum[2] + wsum[3]);
  } else {
    // Gram: block p = (b, sg) computes rows [4sg, 4sg+4) of G_b (36x36).
    const int p = blk - 5376;          // 0..575
    const int b = p / 9, sg = p % 9;
#pragma unroll
    for (int r = 0; r < 4; r++)
      ref[r * 256 + tid] =
          ((const float4*)(images + (size_t)(b * Sr + 4 * sg + r) * Dd))[tid];
    __syncthreads();
    const int wv = tid >> 6, lane = tid & 63;
    for (int s2 = wv; s2 < Sr; s2 += 4) {
      const float4* row2 = (const float4*)(images + (size_t)(b * Sr + s2) * Dd);
      float a0 = 0.f, a1 = 0.f, a2 = 0.f, a3 = 0.f;
#pragma unroll
      for (int j = 0; j < 4; j++) {
        float4 c = row2[lane + j * 64];
        float4 r0 = ref[0 * 256 + lane + j * 64];
        float4 r1 = ref[1 * 256 + lane + j * 64];
        float4 r2 = ref[2 * 256 + lane + j * 64];
        float4 r3 = ref[3 * 256 + lane + j * 64];
        a0 += r0.x * c.x + r0.y * c.y + r0.z * c.z + r0.w * c.w;
        a1 += r1.x * c.x + r1.y * c.y + r1.z * c.z + r1.w * c.w;
        a2 += r2.x * c.x + r2.y * c.y + r2.z * c.z + r2.w * c.w;
        a3 += r3.x * c.x + r3.y * c.y + r3.z * c.z + r3.w * c.w;
      }
#pragma unroll
      for (int o = 32; o; o >>= 1) {
        a0 += __shfl_xor(a0, o); a1 += __shfl_xor(a1, o);
        a2 += __shfl_xor(a2, o); a3 += __shfl_xor(a3, o);
      }
      if (lane == 0) {
        float* gr = G + (size_t)b * Sr * Sr;
        gr[(4 * sg + 0) * Sr + s2] = a0;
        gr[(4 * sg + 1) * Sr + s2] = a1;
        gr[(4 * sg + 2) * Sr + s2] = a2;
        gr[(4 * sg + 3) * Sr + s2] = a3;
      }
    }
  }
}

// ---------------------------------------------------------------------------
// GEMM1 (E_compact = capC @ W^T): 64x64 tiles, BK=64, double-buffered,
// XOR-swizzled LDS. DENSE TILE REMAP: block wid takes the wid-th working
// tile of the compacted M-range (Vpad rows); wid >= nTiles exits. Working
// tiles land on consecutive block IDs -> even CU distribution (R4's striped
// early-exit left max-loaded CUs unchanged -> null result).
// ---------------------------------------------------------------------------
template <int BM, int BN, int MINW>
__global__ __launch_bounds__(256, MINW) void mfma_gemm_dbuf(
    const short* __restrict__ A, const short* __restrict__ B,
    short* __restrict__ C, const int* __restrict__ lens, int K, int ldc)
{
  constexpr int FI = BM / 32;
  constexpr int FJ = BN / 32;
  __shared__ __align__(16) short LA[2][BM * 64];
  __shared__ __align__(16) short LB[2][BN * 64];

  const int t   = threadIdx.x;
  const int wid = blockIdx.y * gridDim.x + blockIdx.x;

  const int V = total_valid(lens, t);
  const int mt = ((V + 63) & ~63) >> 6;   // working m-tiles (BM=64)
  if (wid >= mt * 16) return;             // uniform exit, before any barrier
  // 16 n-tiles (N=1024, BN=64); consecutive wids share the m-stripe
  const int m0 = (wid >> 4) * BM;
  const int n0 = (wid & 15) * BN;

  const int lane = t & 63;
  const int w    = t >> 6;
  const int wm   = w >> 1;
  const int wn   = w & 1;

  const int rIn = t >> 3;
  const int ch  = (t & 7) ^ (rIn & 7);
  const short* gA = A + (size_t)(m0 + rIn) * K + ch * 8;
  const short* gB = B + (size_t)(n0 + rIn) * K + ch * 8;

  const int fr = lane & 15;
  const int fq = lane >> 4;
  const int p0 = fq ^ (fr & 7);

  frag_cd acc[FI][FJ] = {};

  auto stage = [&](int buf, int k0) {
#pragma unroll
    for (int j = 0; j < BM / 32; j++)
      gload16(gA + (size_t)j * 32 * K + k0, &LA[buf][j * 2048 + w * 512]);
#pragma unroll
    for (int j = 0; j < BN / 32; j++)
      gload16(gB + (size_t)j * 32 * K + k0, &LB[buf][j * 2048 + w * 512]);
  };

  stage(0, 0);
  int cur = 0;
  for (int k0 = 0; k0 < K; k0 += 64) {
    __syncthreads();
    if (k0 + 64 < K) stage(cur ^ 1, k0 + 64);

    const short* aBase = &LA[cur][(wm * (FI * 16) + fr) * 64];
    const short* bBase = &LB[cur][(wn * (FJ * 16) + fr) * 64];
#pragma unroll
    for (int th = 0; th < 2; th++) {
      const int pa = p0 ^ (th * 4);
      frag_ab af[FI], bf[FJ];
#pragma unroll
      for (int i = 0; i < FI; i++)
        af[i] = *(const frag_ab*)(aBase + i * 16 * 64 + pa * 8);
#pragma unroll
      for (int j = 0; j < FJ; j++)
        bf[j] = *(const frag_ab*)(bBase + j * 16 * 64 + pa * 8);
#pragma unroll
      for (int i = 0; i < FI; i++)
#pragma unroll
        for (int j = 0; j < FJ; j++)
          acc[i][j] = __builtin_amdgcn_mfma_f32_16x16x32_bf16(
              af[i], bf[j], acc[i][j], 0, 0, 0);
    }
    cur ^= 1;
  }

  // C/D layout: col = lane&15, row = (lane>>4)*4 + reg  [verified m89/m91]
#pragma unroll
  for (int i = 0; i < FI; i++) {
    int row = m0 + wm * (FI * 16) + i * 16 + fq * 4;
#pragma unroll
    for (int j = 0; j < FJ; j++) {
      int col = n0 + wn * (FJ * 16) + j * 16 + fr;
#pragma unroll
      for (int r = 0; r < 4; r++)
        C[(size_t)(row + r) * ldc + col] = f2bf(acc[i][j][r]);
    }
  }
}

// ---------------------------------------------------------------------------
// GEMM2 (Cbig = images @ Bcat^T): 128-thread / 2-wave blocks, block tile
// 128x64, WAVE tile 64x64 (m97-class), BK=64, single-buffer, XOR-swizzled
// LDS, 6 blocks/CU. Bcat = [E_compact rows 0..Vpad; capC at fixed 2048].
// DENSE TILE REMAP over the compacted N-domain: nx working panels per half,
// 2*nx*18 working tiles assigned to consecutive block IDs; the rest exit.
// ---------------------------------------------------------------------------
__global__ __launch_bounds__(128, 3) void gemm2_w64(
    const short* __restrict__ A, const short* __restrict__ B,
    short* __restrict__ C, const int* __restrict__ lens, int K, int ldc)
{
  const int t   = threadIdx.x;     // 0..127
  const int wid = blockIdx.y * gridDim.x + blockIdx.x;

  const int V  = total_valid(lens, t);
  const int nx = ((V + 63) & ~63) >> 6;   // working 64-col panels per half
  const int tw = 2 * nx;                  // panels per 128-row m-stripe
  if (wid >= tw * 18) return;             // uniform exit, before any barrier
  const int y  = wid / tw;                // m-stripe (consecutive wids share)
  const int r  = wid - y * tw;
  const int xl = (r < nx) ? r : r - nx;
  const int n0 = ((r < nx) ? 0 : 2048) + xl * 64;
  const int m0 = y * 128;

  __shared__ __align__(16) short As[128 * 64];
  __shared__ __align__(16) short Bs[64 * 64];

  const int lane = t & 63;
  const int w    = t >> 6;          // wave 0..1 (m-halves)

  const int rIn = t >> 3;
  const int ch  = (t & 7) ^ (rIn & 7);
  const short* gA = A + (size_t)(m0 + rIn) * K + ch * 8;
  const short* gB = B + (size_t)(n0 + rIn) * K + ch * 8;

  const int fr = lane & 15;
  const int fq = lane >> 4;
  const int p0 = fq ^ (fr & 7);

  frag_cd acc[4][4] = {};

  for (int k0 = 0; k0 < K; k0 += 64) {
    __syncthreads();                 // prev-iter LDS readers done
#pragma unroll
    for (int j = 0; j < 8; j++)      // A: 128 rows, 16 per issue
      gload16(gA + (size_t)j * 16 * K + k0, As + j * 1024 + w * 512);
#pragma unroll
    for (int j = 0; j < 4; j++)      // B: 64 rows
      gload16(gB + (size_t)j * 16 * K + k0, Bs + j * 1024 + w * 512);
    __syncthreads();                 // barrier drains vmcnt -> tile published

    const short* aBase = As + (w * 64 + fr) * 64;
    const short* bBase = Bs + fr * 64;
#pragma unroll
    for (int th = 0; th < 2; th++) {
      const int pa = p0 ^ (th * 4);  // swizzled chunk pos for this k-half
      frag_ab af[4], bf[4];
#pragma unroll
      for (int i = 0; i < 4; i++)
        af[i] = *(const frag_ab*)(aBase + i * 16 * 64 + pa * 8);
#pragma unroll
      for (int j = 0; j < 4; j++)
        bf[j] = *(const frag_ab*)(bBase + j * 16 * 64 + pa * 8);
#pragma unroll
      for (int i = 0; i < 4; i++)
#pragma unroll
        for (int j = 0; j < 4; j++)
          acc[i][j] = __builtin_amdgcn_mfma_f32_16x16x32_bf16(
              af[i], bf[j], acc[i][j], 0, 0, 0);
    }
  }

  // C/D layout: col = lane&15, row = (lane>>4)*4 + reg  [verified m89/m91]
#pragma unroll
  for (int i = 0; i < 4; i++) {
    int row = m0 + w * 64 + i * 16 + fq * 4;
#pragma unroll
    for (int j = 0; j < 4; j++) {
      int col = n0 + j * 16 + fr;
#pragma unroll
      for (int r2 = 0; r2 < 4; r2++)
        C[(size_t)(row + r2) * ldc + col] = f2bf(acc[i][j][r2]);
    }
  }
}

// ---------------------------------------------------------------------------
// Finalize: block = (image b, 4 captions); ONE WAVE PER (b,cap) PAIR.
// Reads compacted Cbig columns off[cap]+l (E-half) / 2048+off[cap]+l
// (cap-half), guarded by l<len (invalid lanes get exact 0, matching the
// reference mask semantics).
// ---------------------------------------------------------------------------
__global__ __launch_bounds__(256) void finalize_kernel(
    const short* __restrict__ Cbig, const float* __restrict__ G,
    const float* __restrict__ w1arr, const int* __restrict__ lens,
    float* __restrict__ out)
{
  const int b   = blockIdx.x;        // image
  const int cg  = blockIdx.y;        // caption group of 4
  const int t   = threadIdx.x;
  const int wv  = t >> 6;            // wave -> caption within group
  const int lane = t & 63;
  const int cap = cg * 4 + wv;
  const int l = lane & 31;
  const int s0 = lane >> 5;

  __shared__ float att[4][Sr][Lm];   // fp32 working attn, per wave
  __shared__ short cims[4][Sr][Lm];  // bf16 cap.img dots, per wave
  __shared__ float Gs[Sr][Sr];       // Gram, shared across waves

  for (int i = t; i < Sr * Sr; i += 256)
    Gs[i / Sr][i % Sr] = G[(size_t)b * Sr * Sr + i];

  // off[cap] via 64-lane exclusive scan of lens
  int myLen = lens[lane];
  int incl = myLen;
#pragma unroll
  for (int d = 1; d < 64; d <<= 1) {
    int p = __shfl_up(incl, d);
    if (lane >= d) incl += p;
  }
  const int off = __shfl(incl - myLen, cap);
  const int len = __shfl(myLen, cap);

  // load + leaky-relu + mask (2 s-rows per step: s = 2k + s0)
#pragma unroll
  for (int k = 0; k < 18; k++) {
    int s = k * 2 + s0;
    size_t row = (size_t)(b * Sr + s) * 4096;
    float x = 0.f;
    short cv = 0;
    if (l < len) {
      x = bf2f(Cbig[row + off + l]);
      x = x > 0.f ? x : 0.1f * x;
      cv = Cbig[row + 2048 + off + l];
    }
    att[wv][s][l] = x;
    cims[wv][s][l] = cv;
  }
  __syncthreads();

  // l2 norm over words l, per region s (half-wave reduction, width 32)
#pragma unroll
  for (int k = 0; k < 18; k++) {
    int s = k * 2 + s0;
    float v = att[wv][s][l];
    float ss = v * v;
#pragma unroll
    for (int o = 16; o; o >>= 1) ss += __shfl_xor(ss, o);
    att[wv][s][l] = v * (1.f / (sqrtf(ss) + EPSF));
  }
  __syncthreads();

  // softmax over regions s, per word l (half 0 only)
  if (s0 == 0) {
    float m = -1e30f;
#pragma unroll
    for (int s = 0; s < Sr; s++) m = fmaxf(m, att[wv][s][l]);
    m *= SMOOTH;
    float sum = 0.f;
#pragma unroll
    for (int s = 0; s < Sr; s++) {
      float e = expf(SMOOTH * att[wv][s][l] - m);
      att[wv][s][l] = e; sum += e;
    }
    float inv = 1.f / sum;
#pragma unroll
    for (int s = 0; s < Sr; s++) att[wv][s][l] *= inv;
  }
  __syncthreads();

  // a into registers; w12 & w2 = a^T G a with outer s split across halves
  float a_reg[Sr];
#pragma unroll
  for (int s = 0; s < Sr; s++) a_reg[s] = att[wv][s][l];
  float w12 = 0.f, w2 = 0.f;
  for (int s = s0 * 18; s < s0 * 18 + 18; s++) {
    float a = a_reg[s];
    w12 += a * bf2f(cims[wv][s][l]);
    float tt = 0.f;
    const float4* grow = (const float4*)Gs[s];
#pragma unroll
    for (int q = 0; q < 9; q++) {
      float4 g = grow[q];                        // broadcast read
      tt += g.x * a_reg[q * 4] + g.y * a_reg[q * 4 + 1] +
            g.z * a_reg[q * 4 + 2] + g.w * a_reg[q * 4 + 3];
    }
    w2 += a * tt;
  }
  w12 += __shfl_xor(w12, 32);
  w2  += __shfl_xor(w2, 32);

  // cosine + LogSumExp over valid words (width-32 reduce; halves identical)
  float w1v = w1arr[cap * Lm + l];
  float denom = fmaxf(w1v * sqrtf(fmaxf(w2, 0.f)), EPSF);
  float rs = w12 / denom;
  float z = (l < len) ? rs * LLSE : -1e30f;
  float m = z;
#pragma unroll
  for (int o = 16; o; o >>= 1) m = fmaxf(m, __shfl_xor(m, o));
  float e = expf(z - m);
#pragma unroll
  for (int o = 16; o; o >>= 1) e += __shfl_xor(e, o);
  if (lane == 0) out[(size_t)b * Bn + cap] = (m + logf(e)) / LLSE;
}

// ---------------------------------------------------------------------------
extern "C" void kernel_launch(void* const* d_in, const int* in_sizes, int n_in,
                              void* d_out, int out_size, void* d_ws, size_t ws_size,
                              hipStream_t stream)
{
  const float* images   = (const float*)d_in[0];  // (64,36,1024)
  const float* captions = (const float*)d_in[1];  // (64,32,1024)
  const int*   cap_lens = (const int*)d_in[2];    // (64,)
  const float* W_g      = (const float*)d_in[3];  // (1024,1024)
  float* out = (float*)d_out;                     // (64,64)

  // Workspace (~34.4 MB):
  short* imgbf = (short*)d_ws;                          // 2304*1024 bf16
  short* Bcat  = imgbf + (size_t)2304 * 1024;           // 4096*1024 bf16:
                                                        //  rows [0,2048): E_compact (valid V rows)
                                                        //  rows [2048,4096): capC (compacted captions)
  short* capC  = Bcat + (size_t)2048 * 1024;
  short* Wbf   = Bcat + (size_t)4096 * 1024;            // 1024*1024 bf16
  short* Cbig  = Wbf + (size_t)1024 * 1024;             // 2304*4096 bf16
  float* Gram  = (float*)(Cbig + (size_t)2304 * 4096);  // 64*36*36 fp32
  float* w1a   = Gram + (size_t)Bn * Sr * Sr;           // 2048 fp32

  // conversions (captions -> compacted) + w1 + gram fused (5952 blocks)
  prep_kernel<<<5952, 256, 0, stream>>>(
      images, imgbf, W_g, Wbf, captions, capC, cap_lens, w1a, Gram);

  // E_compact = capC @ W_g^T (V x 1024 x 1024): 64x64 tiles, dense remap
  // over Vpad rows; ~36% of blocks exit as a contiguous ID range
  mfma_gemm_dbuf<64, 64, 4><<<dim3(1024 / 64, 2048 / 64), 256, 0, stream>>>(
      capC, Wbf, Bcat, cap_lens, Dd, 1024);
  // Cbig = images @ Bcat^T: 128x64 blocks, 2 waves, wave tile 64x64,
  // 6 blocks/CU; dense remap over 2*nx*18 working tiles
  gemm2_w64<<<dim3(4096 / 64, 2304 / 128), 128, 0, stream>>>(
      imgbf, Bcat, Cbig, cap_lens, Dd, 4096);

  // finalize: block = image x 4 captions, one wave per (b,cap)
  finalize_kernel<<<dim3(Bn, Bn / 4), 256, 0, stream>>>(
      Cbig, Gram, w1a, cap_lens, out);
}